// Round 5
// baseline (632.850 us; speedup 1.0000x reference)
//
#include <hip/hip_runtime.h>

// N=524288 rows, K=128, outd=256 cols, num_grid=255
#define M_TOTAL     524288
#define KDIM        128
#define NCOL        256
#define GRID_BLOCKS 512                       // 2 blocks/CU resident, exact
#define WAVES_TOTAL (GRID_BLOCKS * 4)         // 2048 waves, 16 rows each per iter
#define IPW         (M_TOTAL / 16 / WAVES_TOTAL)   // 16 iterations per wave, exact
#define LOG2E       1.44269504088896340736f

typedef _Float16 half8   __attribute__((ext_vector_type(8)));
typedef float    floatx4 __attribute__((ext_vector_type(4)));

// DPP prefix-sum within each 16-lane group (VALU pipe, no DS traffic).
template <int CTRL>
__device__ __forceinline__ float dpp_add_step(float x) {
    int xi = __builtin_bit_cast(int, x);
    int sh = __builtin_amdgcn_update_dpp(0, xi, CTRL, 0xF, 0xF, true);
    return x + __builtin_bit_cast(float, sh);
}
__device__ __forceinline__ float row16_sum(float x) {
    x = dpp_add_step<0x111>(x);  // row_shr:1
    x = dpp_add_step<0x112>(x);  // row_shr:2
    x = dpp_add_step<0x114>(x);  // row_shr:4
    x = dpp_add_step<0x118>(x);  // row_shr:8
    return x;
}

// fp32 -> (hi,lo) fp16 2-pass split for 8 consecutive floats (A-side; numerics
// identical to the proven R2 kernel).
__device__ __forceinline__ void cvt8(const floatx4 pf[2], half8& h, half8& l) {
    const float* f = (const float*)pf;
    #pragma unroll
    for (int j = 0; j < 8; ++j) {
        float a = f[j];
        _Float16 hi = (_Float16)a;
        h[j] = hi;
        l[j] = (_Float16)(a - (float)hi);
    }
}

// R5 structure: W^T (fp16*log2e) lives in LDS (constant, staged once); each wave
// owns 16 rows x ALL 256 cols -> softmax denominator is wave-local (in-lane +
// DPP16), ZERO per-iteration barriers / cross-wave traffic. R2-R4 evidence: the
// old col-split structure was lockstep-latency-bound (wall ~14k cyc/iter vs
// ~1.5k issue; barrier + 2 resident waves/SIMD couldn't overlap phases).
__global__ __attribute__((amdgpu_flat_work_group_size(256, 256), amdgpu_waves_per_eu(2, 4)))
void density_kernel(const float* __restrict__ t,
                    const float* __restrict__ x,
                    const float* __restrict__ w,     // [128][256] row-major
                    const float* __restrict__ bias,  // [256]
                    float* __restrict__ out)
{
    // Wt[col][k], chunk-XOR-swizzled: element (col,k) at
    // Wt[col][((k>>3) ^ (col&15))*8 + (k&7)].  64 KiB.
    __shared__ alignas(16) _Float16 Wt[NCOL][KDIM];

    const int tid  = threadIdx.x;
    const int wave = tid >> 6;
    const int lane = tid & 63;
    const int n    = lane & 15;      // A row-in-16 == C col-in-16
    const int q    = lane >> 4;      // quad selector

    // ---- one-time: stage Wt. thread tid owns col=tid; reads coalesced across
    // threads for each k; writes are bank-uniform under the same swizzle.
    {
        const int col = tid;
        #pragma unroll
        for (int kc = 0; kc < 16; ++kc) {
            half8 h;
            #pragma unroll
            for (int j = 0; j < 8; ++j)
                h[j] = (_Float16)(w[(kc * 8 + j) * NCOL + col] * LOG2E);
            *(half8*)&Wt[col][((kc ^ (col & 15)) * 8)] = h;
        }
    }

    // per-lane bias for the 16 owned col-tiles (col = ct*16 + n)
    float biasv[16];
    #pragma unroll
    for (int ct = 0; ct < 16; ++ct)
        biasv[ct] = bias[ct * 16 + n] * LOG2E;

    __syncthreads();   // Wt ready; read-only hereafter — no more barriers.

    // B-fragment swizzled chunk offsets: chunk(ks) = ks*4+q -> ^ (col&15) = ^ n
    int bofs[4];
    #pragma unroll
    for (int ks = 0; ks < 4; ++ks) bofs[ks] = ((ks * 4 + q) ^ n) * 8;

    // ---- row ownership: global wave gw covers rows gw*16 + ii*(WAVES_TOTAL*16)
    const int gw = blockIdx.x * 4 + wave;
    const int ROW_STRIDE = WAVES_TOTAL * 16;            // 32768 rows / iter step
    const size_t X_ADV = (size_t)ROW_STRIDE * KDIM;     // floats
    const float* xp = x + (size_t)(gw * 16 + n) * KDIM + q * 8;
    const float* tp = t + gw * 16 + q * 4;
    float*       op = out + gw * 16;

    // ---- prologue: issue first tile's loads
    floatx4 pf[4][2];
    #pragma unroll
    for (int ks = 0; ks < 4; ++ks) {
        pf[ks][0] = *(const floatx4*)(xp + ks * 32);
        pf[ks][1] = *(const floatx4*)(xp + ks * 32 + 4);
    }
    floatx4 tv = *(const floatx4*)tp;

    #pragma unroll 1
    for (int ii = 0; ii < IPW; ++ii) {
        // ---- consume pf: fp16 hi/lo A fragments (pf dead after this)
        half8 ahi[4], alo[4];
        #pragma unroll
        for (int ks = 0; ks < 4; ++ks) cvt8(pf[ks], ahi[ks], alo[ks]);
        const floatx4 tvc = tv;

        // ---- issue next tile's loads into pf (consumed next iteration;
        // last iteration re-loads current tile — harmless dummy)
        const size_t xadv = (ii + 1 < IPW) ? X_ADV : 0;
        const int    tadv = (ii + 1 < IPW) ? ROW_STRIDE : 0;
        xp += xadv;
        #pragma unroll
        for (int ks = 0; ks < 4; ++ks) {
            pf[ks][0] = *(const floatx4*)(xp + ks * 32);
            pf[ks][1] = *(const floatx4*)(xp + ks * 32 + 4);
        }
        tp += tadv;
        tv = *(const floatx4*)tp;

        // ---- MFMA: 16 col-tiles x 4 k-steps x (hi+lo). B streamed from LDS,
        // no deps -> compiler pipelines ds_read ahead of MFMA freely.
        floatx4 acc[16];
        #pragma unroll
        for (int ct = 0; ct < 16; ++ct)
            acc[ct] = (floatx4){biasv[ct], biasv[ct], biasv[ct], biasv[ct]};
        #pragma unroll
        for (int ks = 0; ks < 4; ++ks) {
            #pragma unroll
            for (int ct = 0; ct < 16; ++ct) {
                const half8 bh = *(const half8*)&Wt[ct * 16 + n][bofs[ks]];
                acc[ct] = __builtin_amdgcn_mfma_f32_16x16x32_f16(ahi[ks], bh, acc[ct], 0, 0, 0);
                acc[ct] = __builtin_amdgcn_mfma_f32_16x16x32_f16(alo[ks], bh, acc[ct], 0, 0, 0);
            }
        }

        // ---- epilogue: softmax-denominator + hat-function numerator, all
        // wave-local. C layout: row = q*4+r, col = ct*16+n.
        float tg[4];
        #pragma unroll
        for (int r = 0; r < 4; ++r) tg[r] = tvc[r] * 255.0f;
        float s[4]  = {0, 0, 0, 0};
        float nm[4] = {0, 0, 0, 0};
        const float cb = (float)n;
        #pragma unroll
        for (int ct = 0; ct < 16; ++ct) {
            const float cf = cb + (float)(ct * 16);
            #pragma unroll
            for (int r = 0; r < 4; ++r) {
                float e = __builtin_amdgcn_exp2f(acc[ct][r]);
                s[r] += e;
                float wt = fmaxf(0.0f, 1.0f - fabsf(cf - tg[r]));
                nm[r] = fmaf(e, wt, nm[r]);
            }
        }
        #pragma unroll
        for (int r = 0; r < 4; ++r) {
            s[r]  = row16_sum(s[r]);
            nm[r] = row16_sum(nm[r]);
        }
        if (n == 15) {
            #pragma unroll
            for (int r = 0; r < 4; ++r)
                op[q * 4 + r] = nm[r] / s[r];
        }
        op += tadv;
    }
}

extern "C" void kernel_launch(void* const* d_in, const int* in_sizes, int n_in,
                              void* d_out, int out_size, void* d_ws, size_t ws_size,
                              hipStream_t stream) {
    const float* t    = (const float*)d_in[0];
    const float* x    = (const float*)d_in[1];
    const float* wgt  = (const float*)d_in[2];
    const float* bias = (const float*)d_in[3];
    float* out = (float*)d_out;

    density_kernel<<<GRID_BLOCKS, 256, 0, stream>>>(t, x, wgt, bias, out);
}